// Round 1
// baseline (480.155 us; speedup 1.0000x reference)
//
#include <hip/hip_runtime.h>

#define BATCH 8
#define CCH 256
#define NPOS 4096

typedef __bf16 bf16x8 __attribute__((ext_vector_type(8)));
typedef float f32x4 __attribute__((ext_vector_type(4)));
typedef int i32x4 __attribute__((ext_vector_type(4)));

__device__ __forceinline__ unsigned short f2bf(float f) {
  unsigned u = __builtin_bit_cast(unsigned, f);
  u += 0x7fffu + ((u >> 16) & 1u);
  return (unsigned short)(u >> 16);
}

__device__ __forceinline__ bf16x8 ld_bf8(const unsigned short* p) {
  i32x4 t = *reinterpret_cast<const i32x4*>(p);
  return __builtin_bit_cast(bf16x8, t);
}

// ---------------------------------------------------------------- kernel 1
__global__ void cvt_kernel(const float* __restrict__ Wq,
                           const float* __restrict__ Wk,
                           const float* __restrict__ Wv,
                           unsigned short* __restrict__ dst)
{
  const int idx = blockIdx.x * 256 + threadIdx.x;   // 0..196607
  const float* src = (idx < 65536) ? Wq : ((idx < 131072) ? Wk : Wv);
  dst[idx] = f2bf(src[idx & 65535]);
}

// ---------------------------------------------------------------- kernel 2
// Per (b, 64-pos tile): stage x^T into LDS (bf16, padded stride 264),
// MFMA 16x16x32 against Wq/Wk/Wv rows (global/L2), write qT,kT in (N,C)
// and v in (C,N) (v transposed through LDS so stores are coalesced 16B).
__global__ __launch_bounds__(256, 2)
void qkv_kernel(const float* __restrict__ x,
                const unsigned short* __restrict__ Wqb,
                const unsigned short* __restrict__ Wkb,
                const unsigned short* __restrict__ Wvb,
                const float* __restrict__ bq,
                const float* __restrict__ bk,
                const float* __restrict__ bv,
                unsigned short* __restrict__ qT,
                unsigned short* __restrict__ kT,
                unsigned short* __restrict__ vG)
{
  __shared__ unsigned short xT[64 * 264];   // 33792 B, stride 264: bank-spread + 16B aligned rows
  __shared__ unsigned short vt[256 * 72];   // 36864 B, transpose scratch for v

  const int b   = blockIdx.x;
  const int i0  = blockIdx.y * 64;
  const int tid = threadIdx.x;
  const int w   = tid >> 6;
  const int l   = tid & 63;
  const int n   = l & 15;
  const int q4  = l >> 4;

  const float* xb = x + (size_t)b * CCH * NPOS;

  {
    const int i  = tid & 63;
    const int cg = tid >> 6;
    for (int it = 0; it < 32; ++it) {
      const int c0 = (it * 4 + cg) * 2;
      const float f0 = xb[(size_t)c0 * NPOS + i0 + i];
      const float f1 = xb[(size_t)(c0 + 1) * NPOS + i0 + i];
      const unsigned pk = (unsigned)f2bf(f0) | ((unsigned)f2bf(f1) << 16);
      *reinterpret_cast<unsigned*>(&xT[i * 264 + c0]) = pk;
    }
  }
  __syncthreads();

  // A fragments: rows i_local = w*16 + (lane&15), k = quad*8 + j
  bf16x8 afr[8];
#pragma unroll
  for (int kk = 0; kk < 8; ++kk)
    afr[kk] = ld_bf8(&xT[(w * 16 + n) * 264 + kk * 32 + q4 * 8]);

  const size_t qbase = (size_t)b * NPOS * CCH;

#pragma unroll
  for (int sel = 0; sel < 2; ++sel) {
    const unsigned short* Wb = sel ? Wkb : Wqb;
    const float* bias = sel ? bk : bq;
    unsigned short* dstb = (sel ? kT : qT) + qbase;
#pragma unroll
    for (int nt = 0; nt < 16; ++nt) {
      const int o = nt * 16 + n;
      f32x4 acc = {0.f, 0.f, 0.f, 0.f};
#pragma unroll
      for (int kk = 0; kk < 8; ++kk) {
        bf16x8 bfr = ld_bf8(Wb + o * CCH + kk * 32 + q4 * 8);   // B[k=c][n=o] = W[o][c], contiguous in c
        acc = __builtin_amdgcn_mfma_f32_16x16x32_bf16(afr[kk], bfr, acc, 0, 0, 0);
      }
      const float bo = bias[o];
#pragma unroll
      for (int r = 0; r < 4; ++r) {
        const float v0 = acc[r] + bo;
        const float v1 = __shfl_xor(v0, 1);        // partner holds o+1 (bias already added)
        if ((l & 1) == 0) {
          const unsigned pk = (unsigned)f2bf(v0) | ((unsigned)f2bf(v1) << 16);
          const int row = i0 + w * 16 + q4 * 4 + r;
          *reinterpret_cast<unsigned*>(&dstb[(size_t)row * CCH + o]) = pk;
        }
      }
    }
  }

  // V: compute, transpose via LDS, store (C,N) coalesced
#pragma unroll
  for (int nt = 0; nt < 16; ++nt) {
    const int o = nt * 16 + n;
    f32x4 acc = {0.f, 0.f, 0.f, 0.f};
#pragma unroll
    for (int kk = 0; kk < 8; ++kk) {
      bf16x8 bfr = ld_bf8(Wvb + o * CCH + kk * 32 + q4 * 8);
      acc = __builtin_amdgcn_mfma_f32_16x16x32_bf16(afr[kk], bfr, acc, 0, 0, 0);
    }
    const float bo = bv[o];
#pragma unroll
    for (int r = 0; r < 4; ++r)
      vt[o * 72 + w * 16 + q4 * 4 + r] = f2bf(acc[r] + bo);
  }
  __syncthreads();

  for (int it = 0; it < 8; ++it) {
    const int idx = it * 256 + tid;
    const int o = idx >> 3;
    const int jw = (idx & 7) * 8;
    i32x4 d = *reinterpret_cast<const i32x4*>(&vt[o * 72 + jw]);
    *reinterpret_cast<i32x4*>(&vG[qbase + (size_t)o * NPOS + i0 + jw]) = d;
  }
}

// ---------------------------------------------------------------- kernel 3
// Flash attention: Br=64 (4 waves x 16 rows), Bc=64, online softmax,
// fused epilogue y = x + gamma * O / l.  batch -> blockIdx.x (XCD-pinned).
__global__ __launch_bounds__(256, 2)
void attn_kernel(const unsigned short* __restrict__ qT,
                 const unsigned short* __restrict__ kT,
                 const unsigned short* __restrict__ vG,
                 const float* __restrict__ x,
                 const float* __restrict__ gamma,
                 float* __restrict__ out)
{
  __shared__ unsigned short kblk[64 * 264];   // 33792 B  K tile, (j,c) padded
  __shared__ unsigned short vblk[256 * 72];   // 36864 B  V tile, (c,j) padded
  __shared__ unsigned short pbuf[64 * 72];    //  9216 B  P (i,j) bf16
  __shared__ float stat_lds[64];              //   256 B  alpha / l broadcast

  const int b   = blockIdx.x;
  const int i0  = blockIdx.y * 64;
  const int tid = threadIdx.x;
  const int w   = tid >> 6;
  const int l   = tid & 63;
  const int n   = l & 15;
  const int q4  = l >> 4;

  const unsigned short* qTb = qT + (size_t)b * NPOS * CCH;
  const unsigned short* kTb = kT + (size_t)b * NPOS * CCH;
  const unsigned short* vb  = vG + (size_t)b * NPOS * CCH;

  // Q fragments held in registers for the whole kernel (A[m=lane&15][k=quad*8+j])
  bf16x8 afr[8];
  {
    const unsigned short* qrow = qTb + (size_t)(i0 + w * 16 + n) * CCH + q4 * 8;
#pragma unroll
    for (int kk = 0; kk < 8; ++kk)
      afr[kk] = ld_bf8(qrow + kk * 32);
  }

  f32x4 O[16];   // [ct*4+it]: c in [w*64+ct*16, +16), i in [it*16, +16)
#pragma unroll
  for (int t = 0; t < 16; ++t) O[t] = {0.f, 0.f, 0.f, 0.f};
  float mrow[4] = {-1e30f, -1e30f, -1e30f, -1e30f};
  float lrow[4] = {0.f, 0.f, 0.f, 0.f};

  for (int jt = 0; jt < 64; ++jt) {
    const int j0 = jt * 64;
    __syncthreads();                       // prev iter's V/P/alpha reads done
    // stage K tile (rows j, contiguous c)
    for (int it = 0; it < 8; ++it) {
      const int idx = it * 256 + tid;
      const int row = idx >> 5;
      const int cw = (idx & 31) * 8;
      i32x4 d = *reinterpret_cast<const i32x4*>(kTb + (size_t)(j0 + row) * CCH + cw);
      *reinterpret_cast<i32x4*>(&kblk[row * 264 + cw]) = d;
    }
    // stage V tile (rows c, 64 j's)
    for (int it = 0; it < 8; ++it) {
      const int idx = it * 256 + tid;
      const int c = idx >> 3;
      const int jw = (idx & 7) * 8;
      i32x4 d = *reinterpret_cast<const i32x4*>(vb + (size_t)c * NPOS + j0 + jw);
      *reinterpret_cast<i32x4*>(&vblk[c * 72 + jw]) = d;
    }
    __syncthreads();

    // S = Q K^T : D[m=i][n=j], k=c.  Rows (lane>>4)*4+reg, col lane&15.
    f32x4 sacc[4];
#pragma unroll
    for (int nt = 0; nt < 4; ++nt) {
      sacc[nt] = {0.f, 0.f, 0.f, 0.f};
#pragma unroll
      for (int kk = 0; kk < 8; ++kk) {
        bf16x8 bfr = ld_bf8(&kblk[(nt * 16 + n) * 264 + kk * 32 + q4 * 8]);
        sacc[nt] = __builtin_amdgcn_mfma_f32_16x16x32_bf16(afr[kk], bfr, sacc[nt], 0, 0, 0);
      }
    }

    // online softmax: row r lives in quad q4 (row = q4*4+r), 16-lane reduce
    float a_r[4];
#pragma unroll
    for (int r = 0; r < 4; ++r) {
      float tm = fmaxf(fmaxf(sacc[0][r], sacc[1][r]), fmaxf(sacc[2][r], sacc[3][r]));
      tm = fmaxf(tm, __shfl_xor(tm, 1));
      tm = fmaxf(tm, __shfl_xor(tm, 2));
      tm = fmaxf(tm, __shfl_xor(tm, 4));
      tm = fmaxf(tm, __shfl_xor(tm, 8));
      const float mnew = fmaxf(mrow[r], tm);
      a_r[r] = __expf(mrow[r] - mnew);
      float s = 0.f;
#pragma unroll
      for (int nt = 0; nt < 4; ++nt) {
        const float p = __expf(sacc[nt][r] - mnew);
        sacc[nt][r] = p;
        s += p;
      }
      s += __shfl_xor(s, 1);
      s += __shfl_xor(s, 2);
      s += __shfl_xor(s, 4);
      s += __shfl_xor(s, 8);
      lrow[r] = lrow[r] * a_r[r] + s;
      mrow[r] = mnew;
    }

    if (n == 0) {
#pragma unroll
      for (int r = 0; r < 4; ++r) stat_lds[w * 16 + q4 * 4 + r] = a_r[r];
    }
    // write P (bf16) to LDS; pair even/odd columns via shfl for 4B writes
#pragma unroll
    for (int r = 0; r < 4; ++r) {
#pragma unroll
      for (int nt = 0; nt < 4; ++nt) {
        const float v0 = sacc[nt][r];
        const float v1 = __shfl_xor(v0, 1);
        if ((l & 1) == 0) {
          const unsigned pk = (unsigned)f2bf(v0) | ((unsigned)f2bf(v1) << 16);
          *reinterpret_cast<unsigned*>(&pbuf[(w * 16 + q4 * 4 + r) * 72 + nt * 16 + n]) = pk;
        }
      }
    }
    __syncthreads();   // P + alpha visible; all K-tile reads done

    // rescale O by alpha[i] (i = it*16 + lane&15)
#pragma unroll
    for (int it = 0; it < 4; ++it) {
      const float al = stat_lds[it * 16 + n];
#pragma unroll
      for (int ct = 0; ct < 4; ++ct) {
        f32x4& o = O[ct * 4 + it];
        o[0] *= al; o[1] *= al; o[2] *= al; o[3] *= al;
      }
    }

    // PV: D[m=c][n=i] += V[c][j] * P[i][j]; wave covers c in [w*64, w*64+64)
    bf16x8 pf[8];
#pragma unroll
    for (int it = 0; it < 4; ++it) {
      pf[it * 2 + 0] = ld_bf8(&pbuf[(it * 16 + n) * 72 + q4 * 8]);
      pf[it * 2 + 1] = ld_bf8(&pbuf[(it * 16 + n) * 72 + 32 + q4 * 8]);
    }
#pragma unroll
    for (int ct = 0; ct < 4; ++ct) {
      bf16x8 vf0 = ld_bf8(&vblk[(w * 64 + ct * 16 + n) * 72 + q4 * 8]);
      bf16x8 vf1 = ld_bf8(&vblk[(w * 64 + ct * 16 + n) * 72 + 32 + q4 * 8]);
#pragma unroll
      for (int it = 0; it < 4; ++it) {
        O[ct * 4 + it] = __builtin_amdgcn_mfma_f32_16x16x32_bf16(vf0, pf[it * 2 + 0], O[ct * 4 + it], 0, 0, 0);
        O[ct * 4 + it] = __builtin_amdgcn_mfma_f32_16x16x32_bf16(vf1, pf[it * 2 + 1], O[ct * 4 + it], 0, 0, 0);
      }
    }
  }

  // epilogue: y = x + gamma * O / l   (coalesced along positions)
  __syncthreads();
  if (n == 0) {
#pragma unroll
    for (int r = 0; r < 4; ++r) stat_lds[w * 16 + q4 * 4 + r] = lrow[r];
  }
  __syncthreads();

  const float g = gamma[0];
#pragma unroll
  for (int it = 0; it < 4; ++it) {
    const float sc = g / stat_lds[it * 16 + n];
    const int ipos = i0 + it * 16 + n;
#pragma unroll
    for (int ct = 0; ct < 4; ++ct) {
#pragma unroll
      for (int r = 0; r < 4; ++r) {
        const int c = w * 64 + ct * 16 + q4 * 4 + r;
        const size_t idx = ((size_t)(b * CCH + c)) * NPOS + ipos;
        out[idx] = x[idx] + sc * O[ct * 4 + it][r];
      }
    }
  }
}

// ---------------------------------------------------------------- launch
extern "C" void kernel_launch(void* const* d_in, const int* in_sizes, int n_in,
                              void* d_out, int out_size, void* d_ws, size_t ws_size,
                              hipStream_t stream)
{
  const float* x     = (const float*)d_in[0];
  const float* Wq    = (const float*)d_in[1];
  const float* bq    = (const float*)d_in[2];
  const float* Wk    = (const float*)d_in[3];
  const float* bk    = (const float*)d_in[4];
  const float* Wv    = (const float*)d_in[5];
  const float* bv    = (const float*)d_in[6];
  const float* gamma = (const float*)d_in[7];
  float* out = (float*)d_out;

  unsigned short* ws  = (unsigned short*)d_ws;
  unsigned short* Wqb = ws;                                   // 65536 elems
  unsigned short* Wkb = ws + 65536;
  unsigned short* Wvb = ws + 131072;
  unsigned short* qT  = ws + 196608;                          // (B,N,C) bf16
  unsigned short* kT  = qT + (size_t)BATCH * NPOS * CCH;      // (B,N,C) bf16
  unsigned short* vG  = kT + (size_t)BATCH * NPOS * CCH;      // (B,C,N) bf16
  // total ws use: ~50.7 MB

  cvt_kernel<<<768, 256, 0, stream>>>(Wq, Wk, Wv, Wqb);
  qkv_kernel<<<dim3(8, 64), 256, 0, stream>>>(x, Wqb, Wkb, Wvb, bq, bk, bv, qT, kT, vG);
  attn_kernel<<<dim3(8, 64), 256, 0, stream>>>(qT, kT, vG, x, gamma, out);
}

// Round 2
// 353.973 us; speedup vs baseline: 1.3565x; 1.3565x over previous
//
#include <hip/hip_runtime.h>

#define BATCH 8
#define CCH 256
#define NPOS 4096

typedef __bf16 bf16x8 __attribute__((ext_vector_type(8)));
typedef float f32x4 __attribute__((ext_vector_type(4)));
typedef int i32x4 __attribute__((ext_vector_type(4)));

typedef const __attribute__((address_space(1))) void GAS;
typedef __attribute__((address_space(3))) void LAS;

#define CFENCE() __asm__ volatile("" ::: "memory")
// vmcnt(8), lgkmcnt no-wait(15), expcnt no-wait(7): (15<<8)|(7<<4)|8
#define WAIT_VM8()  do { CFENCE(); __builtin_amdgcn_s_waitcnt(0x0F78); CFENCE(); } while (0)
// lgkmcnt(0), vmcnt no-wait(63: low4=15,hi2=3), expcnt no-wait
#define WAIT_LGKM0() do { CFENCE(); __builtin_amdgcn_s_waitcnt(0xC07F); CFENCE(); } while (0)
#define BAR_RAW() do { CFENCE(); __builtin_amdgcn_s_barrier(); CFENCE(); } while (0)

__device__ __forceinline__ unsigned short f2bf(float f) {
  unsigned u = __builtin_bit_cast(unsigned, f);
  u += 0x7fffu + ((u >> 16) & 1u);
  return (unsigned short)(u >> 16);
}

__device__ __forceinline__ bf16x8 ld_bf8(const unsigned short* p) {
  i32x4 t = *reinterpret_cast<const i32x4*>(p);
  return __builtin_bit_cast(bf16x8, t);
}

// ---------------------------------------------------------------- kernel 1
__global__ void cvt_kernel(const float* __restrict__ Wq,
                           const float* __restrict__ Wk,
                           const float* __restrict__ Wv,
                           unsigned short* __restrict__ dst)
{
  const int idx = blockIdx.x * 256 + threadIdx.x;   // 0..196607
  const float* src = (idx < 65536) ? Wq : ((idx < 131072) ? Wk : Wv);
  dst[idx] = f2bf(src[idx & 65535]);
}

// ---------------------------------------------------------------- kernel 2
// o-phase blocks: W strip (16 rows x 256) register-resident as A operand,
// x-tile B-frags from LDS shared across q/k/v. Grid (8, 64 pos-tiles, 4 o-phases).
__global__ __launch_bounds__(256, 3)
void qkv_kernel(const float* __restrict__ x,
                const unsigned short* __restrict__ Wall,   // Wq|Wk|Wv bf16
                const float* __restrict__ bq,
                const float* __restrict__ bk,
                const float* __restrict__ bv,
                unsigned short* __restrict__ qT,
                unsigned short* __restrict__ kT,
                unsigned short* __restrict__ vG)
{
  __shared__ __align__(16) unsigned short xT[64 * 264];   // 33792 B
  __shared__ __align__(16) unsigned short tbuf[64 * 72];  //  9216 B transpose buf

  const int b     = blockIdx.x;
  const int i0    = blockIdx.y * 64;
  const int obase = blockIdx.z * 64;
  const int tid = threadIdx.x;
  const int w   = tid >> 6;
  const int l   = tid & 63;
  const int n   = l & 15;
  const int q4  = l >> 4;

  // stage x tile: thread = channel, float4 over positions
  {
    const float* xp = x + ((size_t)b * CCH + tid) * NPOS + i0;
#pragma unroll
    for (int it = 0; it < 16; ++it) {
      f32x4 f = *reinterpret_cast<const f32x4*>(xp + it * 4);
#pragma unroll
      for (int e = 0; e < 4; ++e) xT[(it * 4 + e) * 264 + tid] = f2bf(f[e]);
    }
  }
  __syncthreads();

  const size_t qbase = (size_t)b * NPOS * CCH;

  for (int s = 0; s < 3; ++s) {
    // A = W rows [obase + w*16 .. +16), register resident (8 frags)
    const unsigned short* Wp = Wall + s * 65536 + (size_t)(obase + w * 16 + n) * CCH + q4 * 8;
    bf16x8 wfr[8];
#pragma unroll
    for (int kk = 0; kk < 8; ++kk) wfr[kk] = ld_bf8(Wp + kk * 32);

    const float* bias = (s == 0) ? bq : (s == 1) ? bk : bv;
    float bo[4];
#pragma unroll
    for (int r = 0; r < 4; ++r) bo[r] = bias[obase + w * 16 + q4 * 4 + r];

    f32x4 acc[4];
#pragma unroll
    for (int pt = 0; pt < 4; ++pt) {
      acc[pt] = {0.f, 0.f, 0.f, 0.f};
#pragma unroll
      for (int kk = 0; kk < 8; ++kk) {
        bf16x8 bfr = ld_bf8(&xT[(pt * 16 + n) * 264 + kk * 32 + q4 * 8]);
        acc[pt] = __builtin_amdgcn_mfma_f32_16x16x32_bf16(wfr[kk], bfr, acc[pt], 0, 0, 0);
      }
    }

    if (s) __syncthreads();     // tbuf consumed by previous sel's store
    // D layout: col = lane&15 = pos, row = o-local = w*16 + q4*4 + r
    if (s < 2) {
#pragma unroll
      for (int pt = 0; pt < 4; ++pt)
#pragma unroll
        for (int r = 0; r < 4; ++r)
          tbuf[(pt * 16 + n) * 72 + w * 16 + q4 * 4 + r] = f2bf(acc[pt][r] + bo[r]);
    } else {
#pragma unroll
      for (int pt = 0; pt < 4; ++pt)
#pragma unroll
        for (int r = 0; r < 4; ++r)
          tbuf[(w * 16 + q4 * 4 + r) * 72 + pt * 16 + n] = f2bf(acc[pt][r] + bo[r]);
    }
    __syncthreads();

    if (s < 2) {
      unsigned short* dst = (s == 0 ? qT : kT) + qbase;
#pragma unroll
      for (int it = 0; it < 2; ++it) {
        const int idx = it * 256 + tid;
        const int pos = idx >> 3, ow = (idx & 7) * 8;
        i32x4 d = *reinterpret_cast<const i32x4*>(&tbuf[pos * 72 + ow]);
        *reinterpret_cast<i32x4*>(&dst[(size_t)(i0 + pos) * CCH + obase + ow]) = d;
      }
    } else {
#pragma unroll
      for (int it = 0; it < 2; ++it) {
        const int idx = it * 256 + tid;
        const int o = idx >> 3, pw = (idx & 7) * 8;
        i32x4 d = *reinterpret_cast<const i32x4*>(&tbuf[o * 72 + pw]);
        *reinterpret_cast<i32x4*>(&vG[qbase + (size_t)(obase + o) * NPOS + i0 + pw]) = d;
      }
    }
  }
}

// ---------------------------------------------------------------- kernel 3
// Flash attention, restructured:
//  - K: async global_load_lds (width 16) into XOR-swizzled unpadded double buffer
//  - V: per-lane b128 loads straight from global (L2), prefetched at iter top
//  - 2 raw barriers/iter, explicit vmcnt(8): K[jt+1] DMA stays in flight across PV
__global__ __launch_bounds__(256, 2)
void attn_kernel(const unsigned short* __restrict__ qT,
                 const unsigned short* __restrict__ kT,
                 const unsigned short* __restrict__ vG,
                 const float* __restrict__ x,
                 const float* __restrict__ gamma,
                 float* __restrict__ out)
{
  __shared__ __align__(16) unsigned short kbuf[2][64 * 256];  // 2 x 32768 B, swizzled
  __shared__ __align__(16) unsigned short pbuf[64 * 72];      //  9216 B
  __shared__ float stat_lds[64];

  const int b   = blockIdx.x;
  const int i0  = blockIdx.y * 64;
  const int tid = threadIdx.x;
  const int w   = tid >> 6;
  const int l   = tid & 63;
  const int n   = l & 15;
  const int q4  = l >> 4;
  const int nsw = n & 7;

  const unsigned short* qTb = qT + (size_t)b * NPOS * CCH;
  const unsigned short* kTb = kT + (size_t)b * NPOS * CCH;
  const unsigned short* vb  = vG + (size_t)b * NPOS * CCH;

  // Q fragments register-resident (A[m=lane&15][k=quad*8+j])
  bf16x8 afr[8];
  {
    const unsigned short* qrow = qTb + (size_t)(i0 + w * 16 + n) * CCH + q4 * 8;
#pragma unroll
    for (int kk = 0; kk < 8; ++kk)
      afr[kk] = ld_bf8(qrow + kk * 32);
  }

  // stage K[0]: wave issues 8 DMA loads, instruction t covers local rows 2t,2t+1.
  // LDS granule (j,gp) holds logical granule g = gp ^ (j&7)  (bank-spread swizzle).
  {
#pragma unroll
    for (int it = 0; it < 8; ++it) {
      const int t = w * 8 + it;
      const int j = 2 * t + (l >> 5);
      const int gp = l & 31;
      const int g  = gp ^ (j & 7);
      const unsigned short* src = kTb + (size_t)j * CCH + g * 8;
      unsigned short* dst = &kbuf[0][t * 512];    // wave-uniform base
      __builtin_amdgcn_global_load_lds((GAS*)src, (LAS*)dst, 16, 0, 0);
    }
  }

  f32x4 O[16];   // [ct*4+it]: c in [w*64+ct*16,+16), i in [it*16,+16)
#pragma unroll
  for (int t = 0; t < 16; ++t) O[t] = {0.f, 0.f, 0.f, 0.f};
  float mrow[4] = {-1e30f, -1e30f, -1e30f, -1e30f};
  float lrow[4] = {0.f, 0.f, 0.f, 0.f};

  for (int jt = 0; jt < 64; ++jt) {
    const int j0 = jt * 64;
    const unsigned short* kb = kbuf[jt & 1];

    // prefetch V[jt] into registers (always the 8 NEWEST vmem ops)
    i32x4 vreg[8];
#pragma unroll
    for (int ct = 0; ct < 4; ++ct) {
      const unsigned short* vp = vb + (size_t)(w * 64 + ct * 16 + n) * NPOS + j0 + q4 * 8;
      vreg[ct * 2]     = *reinterpret_cast<const i32x4*>(vp);
      vreg[ct * 2 + 1] = *reinterpret_cast<const i32x4*>(vp + 32);
    }

    WAIT_VM8();     // drain everything older than V[jt] => K[jt] DMA complete
    BAR_RAW();      // all waves' K[jt] in LDS; pbuf/stat free (readers done pre-barrier)

    // S = Q K^T  (swizzled K reads: physical granule = (kk*4+q4) ^ (n&7))
    f32x4 sacc[4];
#pragma unroll
    for (int nt = 0; nt < 4; ++nt) {
      const unsigned short* krow = kb + (nt * 16 + n) * 256;
      sacc[nt] = {0.f, 0.f, 0.f, 0.f};
#pragma unroll
      for (int kk = 0; kk < 8; ++kk) {
        const int gp = (kk * 4 + q4) ^ nsw;
        bf16x8 bfr = ld_bf8(krow + gp * 8);
        sacc[nt] = __builtin_amdgcn_mfma_f32_16x16x32_bf16(afr[kk], bfr, sacc[nt], 0, 0, 0);
      }
    }

    // online softmax (row = q4*4 + r, 16-lane reduce)
    float a_r[4];
#pragma unroll
    for (int r = 0; r < 4; ++r) {
      float tm = fmaxf(fmaxf(sacc[0][r], sacc[1][r]), fmaxf(sacc[2][r], sacc[3][r]));
      tm = fmaxf(tm, __shfl_xor(tm, 1));
      tm = fmaxf(tm, __shfl_xor(tm, 2));
      tm = fmaxf(tm, __shfl_xor(tm, 4));
      tm = fmaxf(tm, __shfl_xor(tm, 8));
      const float mnew = fmaxf(mrow[r], tm);
      a_r[r] = __expf(mrow[r] - mnew);
      float s = 0.f;
#pragma unroll
      for (int nt = 0; nt < 4; ++nt) {
        const float p = __expf(sacc[nt][r] - mnew);
        sacc[nt][r] = p;
        s += p;
      }
      s += __shfl_xor(s, 1);
      s += __shfl_xor(s, 2);
      s += __shfl_xor(s, 4);
      s += __shfl_xor(s, 8);
      lrow[r] = lrow[r] * a_r[r] + s;
      mrow[r] = mnew;
    }

    if (n == 0) {
#pragma unroll
      for (int r = 0; r < 4; ++r) stat_lds[w * 16 + q4 * 4 + r] = a_r[r];
    }
    // P -> LDS, direct u16 writes (no shuffle packing)
#pragma unroll
    for (int r = 0; r < 4; ++r) {
      const int row = w * 16 + q4 * 4 + r;
#pragma unroll
      for (int nt = 0; nt < 4; ++nt)
        pbuf[row * 72 + nt * 16 + n] = f2bf(sacc[nt][r]);
    }

    // prefetch K[jt+1] DMA into other buffer (UNCONDITIONAL, wrapped: keeps
    // compiler's V-use wait at vmcnt(8) instead of vmcnt(0))
    {
      const int j0n = ((jt + 1) & 63) * 64;
      unsigned short* bufn = kbuf[(jt + 1) & 1];
#pragma unroll
      for (int it = 0; it < 8; ++it) {
        const int t = w * 8 + it;
        const int j = 2 * t + (l >> 5);
        const int gp = l & 31;
        const int g  = gp ^ (j & 7);
        const unsigned short* src = kTb + (size_t)(j0n + j) * CCH + g * 8;
        unsigned short* dst = &bufn[t * 512];
        __builtin_amdgcn_global_load_lds((GAS*)src, (LAS*)dst, 16, 0, 0);
      }
    }

    WAIT_LGKM0();   // my P/stat writes landed
    BAR_RAW();      // P + alpha visible to all; K' DMA still in flight

    // rescale O by alpha
#pragma unroll
    for (int it = 0; it < 4; ++it) {
      const float al = stat_lds[it * 16 + n];
#pragma unroll
      for (int ct = 0; ct < 4; ++ct) {
        f32x4& o = O[ct * 4 + it];
        o[0] *= al; o[1] *= al; o[2] *= al; o[3] *= al;
      }
    }

    // PV: V from registers, P from LDS
    bf16x8 pf[8];
#pragma unroll
    for (int it = 0; it < 4; ++it) {
      pf[it * 2 + 0] = ld_bf8(&pbuf[(it * 16 + n) * 72 + q4 * 8]);
      pf[it * 2 + 1] = ld_bf8(&pbuf[(it * 16 + n) * 72 + 32 + q4 * 8]);
    }
#pragma unroll
    for (int ct = 0; ct < 4; ++ct) {
      bf16x8 vf0 = __builtin_bit_cast(bf16x8, vreg[ct * 2]);
      bf16x8 vf1 = __builtin_bit_cast(bf16x8, vreg[ct * 2 + 1]);
#pragma unroll
      for (int it = 0; it < 4; ++it) {
        O[ct * 4 + it] = __builtin_amdgcn_mfma_f32_16x16x32_bf16(vf0, pf[it * 2 + 0], O[ct * 4 + it], 0, 0, 0);
        O[ct * 4 + it] = __builtin_amdgcn_mfma_f32_16x16x32_bf16(vf1, pf[it * 2 + 1], O[ct * 4 + it], 0, 0, 0);
      }
    }
  }

  // epilogue: y = x + gamma * O / l   (full-drain syncthreads fine here)
  __syncthreads();
  if (n == 0) {
#pragma unroll
    for (int r = 0; r < 4; ++r) stat_lds[w * 16 + q4 * 4 + r] = lrow[r];
  }
  __syncthreads();

  const float g = gamma[0];
#pragma unroll
  for (int it = 0; it < 4; ++it) {
    const float sc = g / stat_lds[it * 16 + n];
    const int ipos = i0 + it * 16 + n;
#pragma unroll
    for (int ct = 0; ct < 4; ++ct) {
#pragma unroll
      for (int r = 0; r < 4; ++r) {
        const int c = w * 64 + ct * 16 + q4 * 4 + r;
        const size_t idx = ((size_t)(b * CCH + c)) * NPOS + ipos;
        out[idx] = x[idx] + sc * O[ct * 4 + it][r];
      }
    }
  }
}

// ---------------------------------------------------------------- launch
extern "C" void kernel_launch(void* const* d_in, const int* in_sizes, int n_in,
                              void* d_out, int out_size, void* d_ws, size_t ws_size,
                              hipStream_t stream)
{
  const float* x     = (const float*)d_in[0];
  const float* Wq    = (const float*)d_in[1];
  const float* bq    = (const float*)d_in[2];
  const float* Wk    = (const float*)d_in[3];
  const float* bk    = (const float*)d_in[4];
  const float* Wv    = (const float*)d_in[5];
  const float* bv    = (const float*)d_in[6];
  const float* gamma = (const float*)d_in[7];
  float* out = (float*)d_out;

  unsigned short* ws   = (unsigned short*)d_ws;
  unsigned short* Wall = ws;                                  // 3 x 65536 bf16
  unsigned short* qT   = ws + 196608;                         // (B,N,C) bf16
  unsigned short* kT   = qT + (size_t)BATCH * NPOS * CCH;     // (B,N,C) bf16
  unsigned short* vG   = kT + (size_t)BATCH * NPOS * CCH;     // (B,C,N) bf16

  cvt_kernel<<<768, 256, 0, stream>>>(Wq, Wk, Wv, Wall);
  qkv_kernel<<<dim3(8, 64, 4), 256, 0, stream>>>(x, Wall, bq, bk, bv, qT, kT, vG);
  attn_kernel<<<dim3(8, 64), 256, 0, stream>>>(qT, kT, vG, x, gamma, out);
}